// Round 2
// baseline (2420.832 us; speedup 1.0000x reference)
//
#include <hip/hip_runtime.h>
#include <math.h>

// Problem constants (B=2, T=4096, n=4, D=2048)
#define DM      8192      // n*D flattened feature dim
#define NK      24        // 4 pre + 4 post + 16 res dot products
#define NACC    25        // + 1 for sum(x^2)
#define NTOK    8192      // B*T tokens
#define NGRP    8         // d-groups across blocks
#define DPG     1024      // d per group
#define TPB     256
#define DSUP    256       // d per super-iteration (weights staged in LDS)
#define NSUP    4         // 4 * 256 = 1024 = DPG
#define ITS     8         // inner its per super (each it = 32 d)

// ---------------------------------------------------------------------------
// Kernel 1: Wc[d*24+k] = alpha_k * W_k[d] * rms_w[d]   (d-major, 786 KB)
// ---------------------------------------------------------------------------
__global__ void combine_w(const float* __restrict__ rms_w,
                          const float* __restrict__ w_pre,
                          const float* __restrict__ w_post,
                          const float* __restrict__ w_res,
                          const float* __restrict__ a_pre,
                          const float* __restrict__ a_post,
                          const float* __restrict__ a_res,
                          float* __restrict__ Wc) {
    int idx = blockIdx.x * blockDim.x + threadIdx.x;
    if (idx >= DM * NK) return;
    int d = idx / NK;
    int k = idx - d * NK;
    float w, a;
    if (k < 4)      { w = w_pre [(size_t)k       * DM + d]; a = a_pre[0];  }
    else if (k < 8) { w = w_post[(size_t)(k - 4) * DM + d]; a = a_post[0]; }
    else            { w = w_res [(size_t)(k - 8) * DM + d]; a = a_res[0];  }
    Wc[idx] = a * w * rms_w[d];
}

// ---------------------------------------------------------------------------
// async global->LDS, 16B per lane (dest must be linear: base + lane*16)
// ---------------------------------------------------------------------------
__device__ __forceinline__ void load_lds16(const float* g, float* l) {
    __builtin_amdgcn_global_load_lds(
        (const __attribute__((address_space(1))) void*)g,
        (__attribute__((address_space(3))) void*)l, 16, 0, 0);
}

// ---------------------------------------------------------------------------
// Kernel 2: streaming partial dots, one thread = one token x 8-d stripe.
//   thread t: tg = t>>2 (token in tile), dl = t&3 (d sublane)
//   per it (32 d per block-row): x[tok][dl*8..+8) direct global (128B runs),
//   weights from LDS (24 KB super-block staged via global_load_lds).
//   acc[25] per thread; shfl_xor reduce over 4 dl lanes at the end.
// partial layout: part[(grp*25 + c)*NTOK + token]
// ---------------------------------------------------------------------------
__global__ __launch_bounds__(TPB) void partial_k(const float* __restrict__ x,
                                                 const float* __restrict__ Wc,
                                                 float* __restrict__ part) {
    __shared__ __align__(16) float wlds[DSUP * NK];   // 24 KB, reused as red[]

    const int t    = threadIdx.x;
    const int tile = blockIdx.x;          // 0..127
    const int grp  = blockIdx.y;          // 0..7
    const int tg   = t >> 2;              // token 0..63
    const int dl   = t & 3;               // d sublane 0..3
    const int tok  = tile * 64 + tg;
    const int dbase = grp * DPG;

    const float* xp = x + (size_t)tok * DM + dbase + dl * 8;

    float acc[NACC];
#pragma unroll
    for (int c = 0; c < NACC; ++c) acc[c] = 0.0f;

    // prefetch x for it = 0
    float xc[8], xn[8];
    {
        const float4 a = *(const float4*)(xp + 0);
        const float4 b = *(const float4*)(xp + 4);
        xc[0]=a.x; xc[1]=a.y; xc[2]=a.z; xc[3]=a.w;
        xc[4]=b.x; xc[5]=b.y; xc[6]=b.z; xc[7]=b.w;
    }

    for (int sup = 0; sup < NSUP; ++sup) {
        __syncthreads();                              // protect prev-sup reads
        // stage 256 d x 24 k = 24576 B of weights, linear, 6 x 16B per thread
        const float* wsrc = Wc + (size_t)dbase * NK + sup * (DSUP * NK);
#pragma unroll
        for (int ld = 0; ld < 6; ++ld) {
            const int e4 = (t + ld * TPB) * 4;        // float index, 16B units
            load_lds16(wsrc + e4, &wlds[e4]);
        }
        __syncthreads();                              // drains vmcnt -> staged

#pragma unroll
        for (int it2 = 0; it2 < ITS; ++it2) {
            const int it = sup * ITS + it2;
            // prefetch next it's x (uniform branch; last it has none)
            if (it < NSUP * ITS - 1) {
                const float4 a = *(const float4*)(xp + (it + 1) * 32 + 0);
                const float4 b = *(const float4*)(xp + (it + 1) * 32 + 4);
                xn[0]=a.x; xn[1]=a.y; xn[2]=a.z; xn[3]=a.w;
                xn[4]=b.x; xn[5]=b.y; xn[6]=b.z; xn[7]=b.w;
            }
            // compute: 8 d-rows, 24 coeffs + ss each
            const int drow0 = it2 * 32 + dl * 8;
#pragma unroll
            for (int r = 0; r < 8; ++r) {
                const float xe = xc[r];
                const float* wr = &wlds[(drow0 + r) * NK];
                float w[NK];
#pragma unroll
                for (int j = 0; j < 6; ++j)
                    *(float4*)&w[j * 4] = ((const float4*)wr)[j];
#pragma unroll
                for (int k = 0; k < NK; ++k)
                    acc[k] = fmaf(xe, w[k], acc[k]);
                acc[24] = fmaf(xe, xe, acc[24]);
            }
#pragma unroll
            for (int r = 0; r < 8; ++r) xc[r] = xn[r];
        }
    }

    // ---- reduce over the 4 dl lanes (lanes tg*4 .. tg*4+3) ----
#pragma unroll
    for (int c = 0; c < NACC; ++c) {
        float v = acc[c];
        v += __shfl_xor(v, 1);
        v += __shfl_xor(v, 2);
        acc[c] = v;
    }

    __syncthreads();                                  // before reusing wlds
    float* red = wlds;                                // [64][26]
    if (dl == 0) {
#pragma unroll
        for (int c = 0; c < NACC; ++c) red[tg * 26 + c] = acc[c];
    }
    __syncthreads();

    // coalesced partial write: 64-token runs per coefficient
    const int lt = t & 63;
    const int c0 = t >> 6;                            // 0..3
#pragma unroll
    for (int cc = 0; cc < 7; ++cc) {
        const int c = cc * 4 + c0;
        if (c < NACC)
            part[(size_t)(grp * NACC + c) * NTOK + tile * 64 + lt] =
                red[lt * 26 + c];
    }
}

// ---------------------------------------------------------------------------
// Kernel 3: per-token finalize: sum partials, rstd, sigmoids, Sinkhorn(20).
// ---------------------------------------------------------------------------
__global__ void finalize_k(const float* __restrict__ part,
                           const float* __restrict__ b_pre,
                           const float* __restrict__ b_post,
                           const float* __restrict__ b_res,
                           float* __restrict__ out) {
    const int tk = blockIdx.x * blockDim.x + threadIdx.x;
    if (tk >= NTOK) return;

    float v[NACC];
#pragma unroll
    for (int c = 0; c < NACC; ++c) v[c] = 0.0f;
    for (int g = 0; g < NGRP; ++g) {
#pragma unroll
        for (int c = 0; c < NACC; ++c)
            v[c] += part[(size_t)(g * NACC + c) * NTOK + tk];  // coalesced
    }

    const float rstd = rsqrtf(v[24] * (1.0f / (float)DM) + 1e-6f);

    float* out_pre  = out;                 // [NTOK][4]
    float* out_post = out + (size_t)NTOK * 4;
    float* out_res  = out + (size_t)NTOK * 8;

#pragma unroll
    for (int j = 0; j < 4; ++j) {
        const float lp = fmaf(v[j], rstd, b_pre[j]);
        out_pre[tk * 4 + j] = 1.0f / (1.0f + expf(-lp));
        const float lq = fmaf(v[4 + j], rstd, b_post[j]);
        out_post[tk * 4 + j] = 2.0f / (1.0f + expf(-lq));
    }

    // Sinkhorn-Knopp on 4x4, all in registers, statically indexed
    float M[4][4];
#pragma unroll
    for (int i = 0; i < 4; ++i) {
        float l[4];
#pragma unroll
        for (int j = 0; j < 4; ++j)
            l[j] = fmaf(v[8 + i * 4 + j], rstd, b_res[i * 4 + j]);
        const float m = fmaxf(fmaxf(l[0], l[1]), fmaxf(l[2], l[3]));
#pragma unroll
        for (int j = 0; j < 4; ++j)
            M[i][j] = fmaxf(expf(l[j] - m), 1e-6f);
    }
    for (int it = 0; it < 20; ++it) {
#pragma unroll
        for (int i = 0; i < 4; ++i) {
            const float s = (M[i][0] + M[i][1]) + (M[i][2] + M[i][3]);
            const float inv = 1.0f / fmaxf(s, 1e-6f);
#pragma unroll
            for (int j = 0; j < 4; ++j) M[i][j] *= inv;
        }
#pragma unroll
        for (int j = 0; j < 4; ++j) {
            const float s = (M[0][j] + M[1][j]) + (M[2][j] + M[3][j]);
            const float inv = 1.0f / fmaxf(s, 1e-6f);
#pragma unroll
            for (int i = 0; i < 4; ++i) M[i][j] *= inv;
        }
    }
#pragma unroll
    for (int i = 0; i < 4; ++i)
#pragma unroll
        for (int j = 0; j < 4; ++j)
            out_res[(size_t)tk * 16 + i * 4 + j] = M[i][j];
}

// ---------------------------------------------------------------------------
extern "C" void kernel_launch(void* const* d_in, const int* in_sizes, int n_in,
                              void* d_out, int out_size, void* d_ws, size_t ws_size,
                              hipStream_t stream) {
    const float* x      = (const float*)d_in[0];   // (2,4096,4,2048) fp32
    const float* rms_w  = (const float*)d_in[1];   // (8192,)
    const float* w_pre  = (const float*)d_in[2];   // (4,8192)
    const float* w_post = (const float*)d_in[3];   // (4,8192)
    const float* w_res  = (const float*)d_in[4];   // (16,8192)
    const float* b_pre  = (const float*)d_in[5];   // (4,)
    const float* b_post = (const float*)d_in[6];   // (4,)
    const float* b_res  = (const float*)d_in[7];   // (4,4)
    const float* a_pre  = (const float*)d_in[8];   // scalar
    const float* a_post = (const float*)d_in[9];   // scalar
    const float* a_res  = (const float*)d_in[10];  // scalar
    float* out = (float*)d_out;

    // workspace: Wc (8192*24 floats) then partials (8*25*8192 floats) = 7.34 MB
    float* Wc   = (float*)d_ws;
    float* part = (float*)d_ws + (size_t)DM * NK;

    combine_w<<<(DM * NK + TPB - 1) / TPB, TPB, 0, stream>>>(
        rms_w, w_pre, w_post, w_res, a_pre, a_post, a_res, Wc);

    partial_k<<<dim3(NTOK / 64, NGRP), TPB, 0, stream>>>(x, Wc, part);

    finalize_k<<<NTOK / TPB, TPB, 0, stream>>>(part, b_pre, b_post, b_res, out);
}

// Round 3
// 210.114 us; speedup vs baseline: 11.5215x; 11.5215x over previous
//
#include <hip/hip_runtime.h>
#include <math.h>

// Problem constants (B=2, T=4096, n=4, D=2048)
#define DM      8192      // n*D flattened feature dim
#define NK      24        // 4 pre + 4 post + 16 res dot products
#define NACC    25        // + 1 for sum(x^2)
#define NTOK    8192      // B*T tokens
#define NGRP    32        // d-groups across blocks
#define DPG     256       // d per group (weights LDS-resident: 24 KB)
#define TPB     256
#define TOKB    256       // tokens per block (64 ts * 4 u)
#define UT      4         // tokens per thread
#define NCH     16        // chunks of 16 d (DPG/16); thread covers 4 d/chunk

// ---------------------------------------------------------------------------
// Kernel 1: Wc2[grp][k][dloc] = alpha_k * W_k[grp*256+dloc] * rms_w[...]
// k-major per group so partial_k can stage one linear 24 KB block.
// ---------------------------------------------------------------------------
__global__ void combine_w(const float* __restrict__ rms_w,
                          const float* __restrict__ w_pre,
                          const float* __restrict__ w_post,
                          const float* __restrict__ w_res,
                          const float* __restrict__ a_pre,
                          const float* __restrict__ a_post,
                          const float* __restrict__ a_res,
                          float* __restrict__ Wc2) {
    int idx = blockIdx.x * blockDim.x + threadIdx.x;
    if (idx >= NGRP * NK * DPG) return;
    const int grp  = idx / (NK * DPG);
    const int r    = idx - grp * (NK * DPG);
    const int k    = r / DPG;
    const int dloc = r - k * DPG;
    const int d    = grp * DPG + dloc;
    float w, a;
    if (k < 4)      { w = w_pre [(size_t)k       * DM + d]; a = a_pre[0];  }
    else if (k < 8) { w = w_post[(size_t)(k - 4) * DM + d]; a = a_post[0]; }
    else            { w = w_res [(size_t)(k - 8) * DM + d]; a = a_res[0];  }
    Wc2[idx] = a * w * rms_w[d];
}

// async global->LDS, 16B per lane (dest linear: wave-uniform base + lane*16)
__device__ __forceinline__ void load_lds16(const float* g, float* l) {
    __builtin_amdgcn_global_load_lds(
        (const __attribute__((address_space(1))) void*)g,
        (__attribute__((address_space(3))) void*)l, 16, 0, 0);
}

// ---------------------------------------------------------------------------
// Kernel 2: streaming partials. Block = 256 tokens x 256 d.
//  - weights staged ONCE into LDS (24 KB, k-major), zero main-loop barriers
//  - thread (ts,dl) owns tokens {tile*256+ts+64u}, d-slice dl*4 per chunk
//  - per chunk: 4 prefetch float4 x-loads, 24 ds_read_b128 (conflict-free,
//    16-way broadcast), 400 FMAs; acc[4][25] static; w live window = 4 regs
//  - butterfly shfl over dl; direct partial writes (64 B runs)
// part layout: part[(grp*25 + c)*NTOK + token]
// ---------------------------------------------------------------------------
__global__ __launch_bounds__(TPB, 3) void partial_k(const float* __restrict__ x,
                                                    const float* __restrict__ Wc2,
                                                    float* __restrict__ part) {
    __shared__ __align__(16) float wlds[NK * DPG];   // [24][256] k-major

    const int t    = threadIdx.x;
    const int tile = blockIdx.x;          // 0..31
    const int grp  = blockIdx.y;          // 0..31

    // ---- stage weights once: 24 KB linear ----
    const float* wsrc = Wc2 + (size_t)grp * (NK * DPG);
#pragma unroll
    for (int ld = 0; ld < 6; ++ld) {
        const int e = (t + ld * TPB) * 4;
        load_lds16(wsrc + e, &wlds[e]);
    }

    const int dl  = t & 3;                // d sublane 0..3
    const int ts  = t >> 2;               // token slot 0..63
    const int tok0 = tile * TOKB + ts;    // + 64*u
    const float* xp = x + (size_t)tok0 * DM + grp * DPG + dl * 4;

    float acc[UT][NACC];
#pragma unroll
    for (int u = 0; u < UT; ++u)
#pragma unroll
        for (int c = 0; c < NACC; ++c) acc[u][c] = 0.0f;

    __syncthreads();                      // weights staged (drains vmcnt)

    float xc[UT][4], xn[UT][4];
#pragma unroll
    for (int u = 0; u < UT; ++u) {
        const float4 v = *(const float4*)(xp + (size_t)u * 64 * DM);
        xc[u][0] = v.x; xc[u][1] = v.y; xc[u][2] = v.z; xc[u][3] = v.w;
    }

    for (int c = 0; c < NCH; ++c) {
        if (c + 1 < NCH) {                // uniform branch
#pragma unroll
            for (int u = 0; u < UT; ++u) {
                const float4 v = *(const float4*)(xp + (size_t)u * 64 * DM +
                                                  (c + 1) * 16);
                xn[u][0] = v.x; xn[u][1] = v.y; xn[u][2] = v.z; xn[u][3] = v.w;
            }
        }
        const float* wl = &wlds[c * 16 + dl * 4];
#pragma unroll
        for (int k = 0; k < NK; ++k) {
            const float4 w4 = *(const float4*)(wl + k * DPG);
#pragma unroll
            for (int u = 0; u < UT; ++u) {
                acc[u][k] = fmaf(xc[u][0], w4.x, acc[u][k]);
                acc[u][k] = fmaf(xc[u][1], w4.y, acc[u][k]);
                acc[u][k] = fmaf(xc[u][2], w4.z, acc[u][k]);
                acc[u][k] = fmaf(xc[u][3], w4.w, acc[u][k]);
            }
        }
#pragma unroll
        for (int u = 0; u < UT; ++u)
#pragma unroll
            for (int e = 0; e < 4; ++e)
                acc[u][24] = fmaf(xc[u][e], xc[u][e], acc[u][24]);
        if (c + 1 < NCH) {
#pragma unroll
            for (int u = 0; u < UT; ++u)
#pragma unroll
                for (int e = 0; e < 4; ++e) xc[u][e] = xn[u][e];
        }
    }

    // ---- butterfly reduce over the 4 dl lanes (every lane gets the sum) ----
#pragma unroll
    for (int u = 0; u < UT; ++u)
#pragma unroll
        for (int c = 0; c < NACC; ++c) {
            float v = acc[u][c];
            v += __shfl_xor(v, 1);
            v += __shfl_xor(v, 2);
            acc[u][c] = v;
        }

    // ---- writes: coefficient c handled by lane with c%4==dl (64 B runs) ----
#pragma unroll
    for (int u = 0; u < UT; ++u) {
        const int token = tok0 + 64 * u;
#pragma unroll
        for (int cc = 0; cc < 7; ++cc) {
            const int c = cc * 4 + dl;
            if (c < NACC)
                part[((size_t)grp * NACC + c) * NTOK + token] = acc[u][c];
        }
    }
}

// ---------------------------------------------------------------------------
// Kernel 3: finalize. Block = 64 tokens x 4 g-quarter lanes.
//  Each lane sums 8 groups' partials, butterfly over gq, then ALL 4 lanes
//  duplicate rstd/sigmoid/Sinkhorn (no divergence) and split the writes.
// ---------------------------------------------------------------------------
__global__ void finalize_k(const float* __restrict__ part,
                           const float* __restrict__ b_pre,
                           const float* __restrict__ b_post,
                           const float* __restrict__ b_res,
                           float* __restrict__ out) {
    const int t  = threadIdx.x;
    const int gq = t & 3;
    const int ts = t >> 2;
    const int tk = blockIdx.x * 64 + ts;

    float v[NACC];
#pragma unroll
    for (int c = 0; c < NACC; ++c) v[c] = 0.0f;
    for (int g = gq * 8; g < gq * 8 + 8; ++g) {
#pragma unroll
        for (int c = 0; c < NACC; ++c)
            v[c] += part[((size_t)g * NACC + c) * NTOK + tk];
    }
#pragma unroll
    for (int c = 0; c < NACC; ++c) {
        float s = v[c];
        s += __shfl_xor(s, 1);
        s += __shfl_xor(s, 2);
        v[c] = s;
    }

    const float rstd = rsqrtf(v[24] * (1.0f / (float)DM) + 1e-6f);

    float hp[4], hq[4];
#pragma unroll
    for (int j = 0; j < 4; ++j) {
        const float lp = fmaf(v[j], rstd, b_pre[j]);
        hp[j] = 1.0f / (1.0f + expf(-lp));
        const float lq = fmaf(v[4 + j], rstd, b_post[j]);
        hq[j] = 2.0f / (1.0f + expf(-lq));
    }

    // Sinkhorn-Knopp on 4x4, in registers, duplicated across the 4 gq lanes
    float M[4][4];
#pragma unroll
    for (int i = 0; i < 4; ++i) {
        float l[4];
#pragma unroll
        for (int j = 0; j < 4; ++j)
            l[j] = fmaf(v[8 + i * 4 + j], rstd, b_res[i * 4 + j]);
        const float m = fmaxf(fmaxf(l[0], l[1]), fmaxf(l[2], l[3]));
#pragma unroll
        for (int j = 0; j < 4; ++j)
            M[i][j] = fmaxf(expf(l[j] - m), 1e-6f);
    }
    for (int it = 0; it < 20; ++it) {
#pragma unroll
        for (int i = 0; i < 4; ++i) {
            const float s = (M[i][0] + M[i][1]) + (M[i][2] + M[i][3]);
            const float inv = 1.0f / fmaxf(s, 1e-6f);
#pragma unroll
            for (int j = 0; j < 4; ++j) M[i][j] *= inv;
        }
#pragma unroll
        for (int j = 0; j < 4; ++j) {
            const float s = (M[0][j] + M[1][j]) + (M[2][j] + M[3][j]);
            const float inv = 1.0f / fmaxf(s, 1e-6f);
#pragma unroll
            for (int i = 0; i < 4; ++i) M[i][j] *= inv;
        }
    }

    float* out_pre  = out;                        // [NTOK][4]
    float* out_post = out + (size_t)NTOK * 4;     // [NTOK][4]
    float* out_res  = out + (size_t)NTOK * 8;     // [NTOK][16]
    if (gq == 0) {
        ((float4*)out_pre)[tk] = make_float4(hp[0], hp[1], hp[2], hp[3]);
    } else if (gq == 1) {
        ((float4*)out_post)[tk] = make_float4(hq[0], hq[1], hq[2], hq[3]);
    } else if (gq == 2) {
        ((float4*)out_res)[tk * 4 + 0] = make_float4(M[0][0], M[0][1], M[0][2], M[0][3]);
        ((float4*)out_res)[tk * 4 + 1] = make_float4(M[1][0], M[1][1], M[1][2], M[1][3]);
    } else {
        ((float4*)out_res)[tk * 4 + 2] = make_float4(M[2][0], M[2][1], M[2][2], M[2][3]);
        ((float4*)out_res)[tk * 4 + 3] = make_float4(M[3][0], M[3][1], M[3][2], M[3][3]);
    }
}

// ---------------------------------------------------------------------------
extern "C" void kernel_launch(void* const* d_in, const int* in_sizes, int n_in,
                              void* d_out, int out_size, void* d_ws, size_t ws_size,
                              hipStream_t stream) {
    const float* x      = (const float*)d_in[0];   // (2,4096,4,2048) fp32
    const float* rms_w  = (const float*)d_in[1];   // (8192,)
    const float* w_pre  = (const float*)d_in[2];   // (4,8192)
    const float* w_post = (const float*)d_in[3];   // (4,8192)
    const float* w_res  = (const float*)d_in[4];   // (16,8192)
    const float* b_pre  = (const float*)d_in[5];   // (4,)
    const float* b_post = (const float*)d_in[6];   // (4,)
    const float* b_res  = (const float*)d_in[7];   // (4,4)
    const float* a_pre  = (const float*)d_in[8];   // scalar
    const float* a_post = (const float*)d_in[9];   // scalar
    const float* a_res  = (const float*)d_in[10];  // scalar
    float* out = (float*)d_out;

    // ws: Wc2 (32*24*256 = 196608 floats) then part (32*25*8192 = 6.55M) ~27MB
    float* Wc2  = (float*)d_ws;
    float* part = (float*)d_ws + (size_t)NGRP * NK * DPG;

    combine_w<<<(NGRP * NK * DPG + TPB - 1) / TPB, TPB, 0, stream>>>(
        rms_w, w_pre, w_post, w_res, a_pre, a_post, a_res, Wc2);

    partial_k<<<dim3(NTOK / TOKB, NGRP), TPB, 0, stream>>>(x, Wc2, part);

    finalize_k<<<NTOK / 64, TPB, 0, stream>>>(part, b_pre, b_post, b_res, out);
}

// Round 4
// 95.621 us; speedup vs baseline: 25.3170x; 2.1974x over previous
//
#include <hip/hip_runtime.h>
#include <math.h>

// Problem constants (B=2, T=4096, n=4, D=2048)
#define DM      8192      // n*D flattened feature dim
#define NK      24        // 4 pre + 4 post + 16 res dot products
#define NACC    25        // + 1 for sum(x^2)
#define NTOK    8192      // B*T tokens
#define NGRP    32        // d-groups across blocks
#define DPG     256       // d per group (weights LDS-resident: 24 KB)
#define TPB     256
#define TOKB    128       // tokens per block (32 ts * 4 u)
#define UT      4         // tokens per thread
#define NCH     16        // chunks of 16 d; thread covers 4 d/chunk
#define KHN     12        // coefficients per kh half

// ---------------------------------------------------------------------------
// Kernel 1: Wc2[grp][k][dloc] = alpha_k * W_k[grp*256+dloc] * rms_w[...]
// k-major per group so partial_k can stage one linear 24 KB block.
// ---------------------------------------------------------------------------
__global__ void combine_w(const float* __restrict__ rms_w,
                          const float* __restrict__ w_pre,
                          const float* __restrict__ w_post,
                          const float* __restrict__ w_res,
                          const float* __restrict__ a_pre,
                          const float* __restrict__ a_post,
                          const float* __restrict__ a_res,
                          float* __restrict__ Wc2) {
    int idx = blockIdx.x * blockDim.x + threadIdx.x;
    if (idx >= NGRP * NK * DPG) return;
    const int grp  = idx / (NK * DPG);
    const int r    = idx - grp * (NK * DPG);
    const int k    = r / DPG;
    const int dloc = r - k * DPG;
    const int d    = grp * DPG + dloc;
    float w, a;
    if (k < 4)      { w = w_pre [(size_t)k       * DM + d]; a = a_pre[0];  }
    else if (k < 8) { w = w_post[(size_t)(k - 4) * DM + d]; a = a_post[0]; }
    else            { w = w_res [(size_t)(k - 8) * DM + d]; a = a_res[0];  }
    Wc2[idx] = a * w * rms_w[d];
}

// async global->LDS, 16B per lane (dest linear: wave-uniform base + lane*16)
__device__ __forceinline__ void load_lds16(const float* g, float* l) {
    __builtin_amdgcn_global_load_lds(
        (const __attribute__((address_space(1))) void*)g,
        (__attribute__((address_space(3))) void*)l, 16, 0, 0);
}

// ---------------------------------------------------------------------------
// Kernel 2: streaming partials. Block = 128 tokens x 256 d.
//  thread (ts=t>>3, kh=(t>>2)&1, dl=t&3):
//    - tokens {tile*128 + ts + 32u}, u=0..3
//    - coefficient half kh*12..+12, plus ss (both halves compute ss)
//    - d-slice dl*4 within each 16-d chunk
//  acc[4][13] = 52 regs -> total live ~105, fits 4 waves/SIMD (128 cap).
//  weights staged once in LDS (24 KB, k-major); kh-pair lanes read identical
//  x addresses (L1-merged); w reads 2-way aliased (free). Barrier-free loop.
// part layout: part[(grp*25 + c)*NTOK + token]
// ---------------------------------------------------------------------------
__global__ __launch_bounds__(TPB, 4) void partial_k(const float* __restrict__ x,
                                                    const float* __restrict__ Wc2,
                                                    float* __restrict__ part) {
    __shared__ __align__(16) float wlds[NK * DPG];   // [24][256] k-major, 24 KB

    const int t    = threadIdx.x;
    const int tile = blockIdx.x;          // 0..63
    const int grp  = blockIdx.y;          // 0..31

    // ---- stage weights once: 24 KB linear ----
    const float* wsrc = Wc2 + (size_t)grp * (NK * DPG);
#pragma unroll
    for (int ld = 0; ld < 6; ++ld) {
        const int e = (t + ld * TPB) * 4;
        load_lds16(wsrc + e, &wlds[e]);
    }

    const int dl   = t & 3;               // d sublane 0..3
    const int kh   = (t >> 2) & 1;        // coefficient half 0..1
    const int ts   = t >> 3;              // token slot 0..31
    const int tok0 = tile * TOKB + ts;    // + 32*u
    const float* xp = x + (size_t)tok0 * DM + grp * DPG + dl * 4;

    float acc[UT][13];
#pragma unroll
    for (int u = 0; u < UT; ++u)
#pragma unroll
        for (int kk = 0; kk < 13; ++kk) acc[u][kk] = 0.0f;

    __syncthreads();                      // weights staged (drains vmcnt)

    float xc[UT][4], xn[UT][4];
#pragma unroll
    for (int u = 0; u < UT; ++u) {
        const float4 v = *(const float4*)(xp + (size_t)u * 32 * DM);
        xc[u][0] = v.x; xc[u][1] = v.y; xc[u][2] = v.z; xc[u][3] = v.w;
    }

    for (int c = 0; c < NCH; ++c) {
        if (c + 1 < NCH) {                // uniform branch: prefetch next chunk
#pragma unroll
            for (int u = 0; u < UT; ++u) {
                const float4 v = *(const float4*)(xp + (size_t)u * 32 * DM +
                                                  (c + 1) * 16);
                xn[u][0] = v.x; xn[u][1] = v.y; xn[u][2] = v.z; xn[u][3] = v.w;
            }
        }
        const float* wl = &wlds[kh * (KHN * DPG) + c * 16 + dl * 4];
#pragma unroll
        for (int kk = 0; kk < KHN; ++kk) {
            const float4 w4 = *(const float4*)(wl + kk * DPG);
#pragma unroll
            for (int u = 0; u < UT; ++u) {
                acc[u][kk] = fmaf(xc[u][0], w4.x, acc[u][kk]);
                acc[u][kk] = fmaf(xc[u][1], w4.y, acc[u][kk]);
                acc[u][kk] = fmaf(xc[u][2], w4.z, acc[u][kk]);
                acc[u][kk] = fmaf(xc[u][3], w4.w, acc[u][kk]);
            }
        }
#pragma unroll
        for (int u = 0; u < UT; ++u)
#pragma unroll
            for (int e = 0; e < 4; ++e)
                acc[u][12] = fmaf(xc[u][e], xc[u][e], acc[u][12]);
        if (c + 1 < NCH) {
#pragma unroll
            for (int u = 0; u < UT; ++u)
#pragma unroll
                for (int e = 0; e < 4; ++e) xc[u][e] = xn[u][e];
        }
    }

    // ---- butterfly reduce over the 4 dl lanes ----
#pragma unroll
    for (int u = 0; u < UT; ++u)
#pragma unroll
        for (int kk = 0; kk < 13; ++kk) {
            float v = acc[u][kk];
            v += __shfl_xor(v, 1);
            v += __shfl_xor(v, 2);
            acc[u][kk] = v;
        }

    // ---- reshape via LDS (all register indices static) ----
    __syncthreads();                      // done reading wlds
    float* red = wlds;                    // [(kh*32+ts)*52 + kk*4 + u]
    if (dl == 0) {
        const int base = (kh * 32 + ts) * 52;
#pragma unroll
        for (int kk = 0; kk < 13; ++kk)
#pragma unroll
            for (int u = 0; u < UT; ++u)
                red[base + kk * 4 + u] = acc[u][kk];
    }
    __syncthreads();

    // ---- coalesced partial writes: 64-token (256 B) runs per c-plane ----
    const int tp    = t & 127;            // token within tile block
    const int ch    = t >> 7;             // 0..1, c parity
    const int token = tile * TOKB + tp;
    const int lts   = tp & 31;            // producer ts
    const int lu    = tp >> 5;            // producer u
#pragma unroll
    for (int cc = 0; cc < 13; ++cc) {
        const int c = cc * 2 + ch;
        if (c < NACC) {
            const int khh = (c < 24) ? (c / 12) : 0;
            const int kkk = (c < 24) ? (c - khh * 12) : 12;
            part[((size_t)grp * NACC + c) * NTOK + token] =
                red[(khh * 32 + lts) * 52 + kkk * 4 + lu];
        }
    }
}

// ---------------------------------------------------------------------------
// Kernel 3: finalize. Block = 64 tokens x 4 g-quarter lanes.
// ---------------------------------------------------------------------------
__global__ void finalize_k(const float* __restrict__ part,
                           const float* __restrict__ b_pre,
                           const float* __restrict__ b_post,
                           const float* __restrict__ b_res,
                           float* __restrict__ out) {
    const int t  = threadIdx.x;
    const int gq = t & 3;
    const int ts = t >> 2;
    const int tk = blockIdx.x * 64 + ts;

    float v[NACC];
#pragma unroll
    for (int c = 0; c < NACC; ++c) v[c] = 0.0f;
    for (int g = gq * 8; g < gq * 8 + 8; ++g) {
#pragma unroll
        for (int c = 0; c < NACC; ++c)
            v[c] += part[((size_t)g * NACC + c) * NTOK + tk];
    }
#pragma unroll
    for (int c = 0; c < NACC; ++c) {
        float s = v[c];
        s += __shfl_xor(s, 1);
        s += __shfl_xor(s, 2);
        v[c] = s;
    }

    const float rstd = rsqrtf(v[24] * (1.0f / (float)DM) + 1e-6f);

    float hp[4], hq[4];
#pragma unroll
    for (int j = 0; j < 4; ++j) {
        const float lp = fmaf(v[j], rstd, b_pre[j]);
        hp[j] = 1.0f / (1.0f + expf(-lp));
        const float lq = fmaf(v[4 + j], rstd, b_post[j]);
        hq[j] = 2.0f / (1.0f + expf(-lq));
    }

    // Sinkhorn-Knopp on 4x4, in registers, duplicated across the 4 gq lanes
    float M[4][4];
#pragma unroll
    for (int i = 0; i < 4; ++i) {
        float l[4];
#pragma unroll
        for (int j = 0; j < 4; ++j)
            l[j] = fmaf(v[8 + i * 4 + j], rstd, b_res[i * 4 + j]);
        const float m = fmaxf(fmaxf(l[0], l[1]), fmaxf(l[2], l[3]));
#pragma unroll
        for (int j = 0; j < 4; ++j)
            M[i][j] = fmaxf(expf(l[j] - m), 1e-6f);
    }
    for (int it = 0; it < 20; ++it) {
#pragma unroll
        for (int i = 0; i < 4; ++i) {
            const float s = (M[i][0] + M[i][1]) + (M[i][2] + M[i][3]);
            const float inv = 1.0f / fmaxf(s, 1e-6f);
#pragma unroll
            for (int j = 0; j < 4; ++j) M[i][j] *= inv;
        }
#pragma unroll
        for (int j = 0; j < 4; ++j) {
            const float s = (M[0][j] + M[1][j]) + (M[2][j] + M[3][j]);
            const float inv = 1.0f / fmaxf(s, 1e-6f);
#pragma unroll
            for (int i = 0; i < 4; ++i) M[i][j] *= inv;
        }
    }

    float* out_pre  = out;                        // [NTOK][4]
    float* out_post = out + (size_t)NTOK * 4;     // [NTOK][4]
    float* out_res  = out + (size_t)NTOK * 8;     // [NTOK][16]
    if (gq == 0) {
        ((float4*)out_pre)[tk] = make_float4(hp[0], hp[1], hp[2], hp[3]);
    } else if (gq == 1) {
        ((float4*)out_post)[tk] = make_float4(hq[0], hq[1], hq[2], hq[3]);
    } else if (gq == 2) {
        ((float4*)out_res)[tk * 4 + 0] = make_float4(M[0][0], M[0][1], M[0][2], M[0][3]);
        ((float4*)out_res)[tk * 4 + 1] = make_float4(M[1][0], M[1][1], M[1][2], M[1][3]);
    } else {
        ((float4*)out_res)[tk * 4 + 2] = make_float4(M[2][0], M[2][1], M[2][2], M[2][3]);
        ((float4*)out_res)[tk * 4 + 3] = make_float4(M[3][0], M[3][1], M[3][2], M[3][3]);
    }
}

// ---------------------------------------------------------------------------
extern "C" void kernel_launch(void* const* d_in, const int* in_sizes, int n_in,
                              void* d_out, int out_size, void* d_ws, size_t ws_size,
                              hipStream_t stream) {
    const float* x      = (const float*)d_in[0];   // (2,4096,4,2048) fp32
    const float* rms_w  = (const float*)d_in[1];   // (8192,)
    const float* w_pre  = (const float*)d_in[2];   // (4,8192)
    const float* w_post = (const float*)d_in[3];   // (4,8192)
    const float* w_res  = (const float*)d_in[4];   // (16,8192)
    const float* b_pre  = (const float*)d_in[5];   // (4,)
    const float* b_post = (const float*)d_in[6];   // (4,)
    const float* b_res  = (const float*)d_in[7];   // (4,4)
    const float* a_pre  = (const float*)d_in[8];   // scalar
    const float* a_post = (const float*)d_in[9];   // scalar
    const float* a_res  = (const float*)d_in[10];  // scalar
    float* out = (float*)d_out;

    // ws: Wc2 (32*24*256 = 196608 floats) then part (32*25*8192 = 6.55M) ~27MB
    float* Wc2  = (float*)d_ws;
    float* part = (float*)d_ws + (size_t)NGRP * NK * DPG;

    combine_w<<<(NGRP * NK * DPG + TPB - 1) / TPB, TPB, 0, stream>>>(
        rms_w, w_pre, w_post, w_res, a_pre, a_post, a_res, Wc2);

    partial_k<<<dim3(NTOK / TOKB, NGRP), TPB, 0, stream>>>(x, Wc2, part);

    finalize_k<<<NTOK / 64, TPB, 0, stream>>>(part, b_pre, b_post, b_res, out);
}